// Round 13
// baseline (293.655 us; speedup 1.0000x reference)
//
#include <hip/hip_runtime.h>
#include <hip/hip_bf16.h>

// Dims
#define BB 2
#define TT 197
#define TP 208          // padded T (13*16)
#define NT16 13
#define DIMM 256
#define HEADS_ 4
#define DH_ 64
#define ABCDE_N 1280   // 5*HEADS*DH = 5*256
#define MLP_ 1024
#define NCLS_ 1000
#define PATCH_DIM_ 768

typedef __attribute__((ext_vector_type(8))) short short8_t;   // 8 bf16
typedef __attribute__((ext_vector_type(4))) float f32x4;

__device__ __forceinline__ float waveReduceSum(float v) {
#pragma unroll
    for (int off = 32; off > 0; off >>= 1) v += __shfl_xor(v, off, 64);
    return v;
}

__device__ __forceinline__ unsigned short f2bf(float x) {
    unsigned int u = __float_as_uint(x);
    u += 0x7FFFu + ((u >> 16) & 1u);   // RNE
    return (unsigned short)(u >> 16);
}

__device__ __forceinline__ float bf2f(unsigned short u) {
    return __uint_as_float(((unsigned int)u) << 16);
}

// ---------------------------------------------------------------------------
// Patch embed (unchanged)
// ---------------------------------------------------------------------------
__global__ __launch_bounds__(256) void patch_embed_k(
    const float* __restrict__ img, const float* __restrict__ g1, const float* __restrict__ b1,
    const float* __restrict__ pw, const float* __restrict__ pb,
    const float* __restrict__ g2, const float* __restrict__ b2,
    const float* __restrict__ pos, const float* __restrict__ cls,
    float* __restrict__ xa)
{
    int tid = threadIdx.x;
    if (blockIdx.x == 98) {
        for (int b = 0; b < BB; b++)
            xa[(long)b * TT * DIMM + tid] = cls[tid] + pos[tid];
        return;
    }
    __shared__ __align__(16) float xs[4][PATCH_DIM_];
    __shared__ float red[8];
    int pr0 = blockIdx.x * 4;
    for (int r = 0; r < 4; r++) {
        int pr = pr0 + r;
        int b = pr / 196, patch = pr % 196;
        int gh = patch / 14, gw = patch % 14;
        for (int j = tid; j < PATCH_DIM_; j += 256) {
            int c = j % 3, p2 = (j / 3) % 16, p1 = j / 48;
            xs[r][j] = img[(((long)b * 3 + c) * 224 + gh * 16 + p1) * 224 + gw * 16 + p2];
        }
    }
    __syncthreads();
    int wv = tid >> 6, lane = tid & 63;
    {
        int r = wv;
        float s = 0.f, s2 = 0.f;
        for (int j = lane; j < PATCH_DIM_; j += 64) { float v = xs[r][j]; s += v; s2 += v * v; }
        s = waveReduceSum(s); s2 = waveReduceSum(s2);
        float m = s / PATCH_DIM_;
        float rs = rsqrtf(s2 / PATCH_DIM_ - m * m + 1e-5f);
        for (int j = lane; j < PATCH_DIM_; j += 64)
            xs[r][j] = (xs[r][j] - m) * rs * g1[j] + b1[j];
    }
    __syncthreads();
    float acc[4] = {0.f, 0.f, 0.f, 0.f};
    for (int k = 0; k < PATCH_DIM_; k += 4) {
        float w0 = pw[(k + 0) * DIMM + tid];
        float w1 = pw[(k + 1) * DIMM + tid];
        float w2 = pw[(k + 2) * DIMM + tid];
        float w3 = pw[(k + 3) * DIMM + tid];
#pragma unroll
        for (int r = 0; r < 4; r++) {
            float4 xv = *(const float4*)&xs[r][k];
            acc[r] = fmaf(xv.x, w0, fmaf(xv.y, w1, fmaf(xv.z, w2, fmaf(xv.w, w3, acc[r]))));
        }
    }
#pragma unroll
    for (int r = 0; r < 4; r++) acc[r] += pb[tid];
    for (int r = 0; r < 4; r++) {
        float s = waveReduceSum(acc[r]);
        float s2 = waveReduceSum(acc[r] * acc[r]);
        if (lane == 0) { red[wv * 2] = s; red[wv * 2 + 1] = s2; }
        __syncthreads();
        float S = red[0] + red[2] + red[4] + red[6];
        float S2 = red[1] + red[3] + red[5] + red[7];
        __syncthreads();
        float m = S / DIMM;
        float rs = rsqrtf(S2 / DIMM - m * m + 1e-5f);
        int pr = pr0 + r;
        int b = pr / 196, patch = pr % 196;
        float v = (acc[r] - m) * rs * g2[tid] + b2[tid] + pos[(1 + patch) * DIMM + tid];
        xa[((long)b * TT + 1 + patch) * DIMM + tid] = v;
    }
}

// ---------------------------------------------------------------------------
// K-split GEMM v2 (unchanged from round 12): 512 threads, 8-way K-split.
// ---------------------------------------------------------------------------
__global__ __launch_bounds__(512) void gemm_ksplit_k(
    const float* __restrict__ x, long x_stride, int M, int K, int N,
    const float* __restrict__ w, const float* __restrict__ bias,
    const float* __restrict__ res, float* __restrict__ out,
    const float* __restrict__ ln_g, const float* __restrict__ ln_b,
    int do_gelu)
{
    __shared__ __align__(16) float xs[4 * 1024];
    __shared__ float psum[8 * 4 * 64];   // [wave][row][col]
    int tid = threadIdx.x, lane = tid & 63, wv = tid >> 6;   // wv 0..7
    int row0 = blockIdx.y * 4, col0 = blockIdx.x * 64;

    for (int i = tid; i < 4 * K; i += 512) {
        int r = i / K, k = i - r * K;
        int row = row0 + r;
        xs[i] = (row < M) ? x[(long)row * x_stride + k] : 0.f;
    }
    __syncthreads();
    if (ln_g) {
        if (wv < 4) {   // one wave per row
            float* xr = xs + wv * K;
            float s = 0.f, s2 = 0.f;
            for (int k = lane; k < K; k += 64) { float v = xr[k]; s += v; s2 += v * v; }
            s = waveReduceSum(s); s2 = waveReduceSum(s2);
            float m = s / K;
            float rs = rsqrtf(s2 / K - m * m + 1e-5f);
            for (int k = lane; k < K; k += 64)
                xr[k] = (xr[k] - m) * rs * ln_g[k] + ln_b[k];
        }
        __syncthreads();
    }

    int col = col0 + lane;
    float a0 = 0.f, a1 = 0.f, a2 = 0.f, a3 = 0.f;
    int kq = K >> 3;
    if (col < N) {
        const float* x0 = xs + wv * kq;
        const float* x1 = x0 + K;
        const float* x2 = x1 + K;
        const float* x3 = x2 + K;
        const float* wp = w + (long)(wv * kq) * N + col;
        long nl = N;
        for (int kk = 0; kk < kq; kk += 4) {
            float w0 = wp[0], w1 = wp[nl], w2 = wp[2 * nl], w3 = wp[3 * nl];
            wp += 4 * nl;
            float4 v0 = *(const float4*)(x0 + kk);
            float4 v1 = *(const float4*)(x1 + kk);
            float4 v2 = *(const float4*)(x2 + kk);
            float4 v3 = *(const float4*)(x3 + kk);
            a0 = fmaf(v0.x, w0, fmaf(v0.y, w1, fmaf(v0.z, w2, fmaf(v0.w, w3, a0))));
            a1 = fmaf(v1.x, w0, fmaf(v1.y, w1, fmaf(v1.z, w2, fmaf(v1.w, w3, a1))));
            a2 = fmaf(v2.x, w0, fmaf(v2.y, w1, fmaf(v2.z, w2, fmaf(v2.w, w3, a2))));
            a3 = fmaf(v3.x, w0, fmaf(v3.y, w1, fmaf(v3.z, w2, fmaf(v3.w, w3, a3))));
        }
    }
    psum[wv * 256 + 0 * 64 + lane] = a0;
    psum[wv * 256 + 1 * 64 + lane] = a1;
    psum[wv * 256 + 2 * 64 + lane] = a2;
    psum[wv * 256 + 3 * 64 + lane] = a3;
    __syncthreads();

    if (tid < 256) {
        int r = tid >> 6, c = tid & 63;
        float v = ((psum[r * 64 + c]        + psum[256 + r * 64 + c])
                +  (psum[512 + r * 64 + c]  + psum[768 + r * 64 + c]))
                + ((psum[1024 + r * 64 + c] + psum[1280 + r * 64 + c])
                +  (psum[1536 + r * 64 + c] + psum[1792 + r * 64 + c]));
        int row = row0 + r, cw = col0 + c;
        if (row < M && cw < N) {
            if (bias) v += bias[cw];
            if (do_gelu) v = 0.5f * v * (1.f + erff(v * 0.70710678118654752f));
            if (res) v += res[(long)row * N + cw];
            out[(long)row * N + cw] = v;
        }
    }
}

// ---------------------------------------------------------------------------
// Trittention v7 (MFMA): v3 body with i-axis wave-pair split, 512 threads.
// Grid (ceil(TT/4), BB*HEADS). 8 waves: q = bx*4 + (wv>>1); the pair splits
// A tile-rows (i = wh; i += 2). B-hoist is STATIC (full 26 frags, identical
// to v3's code the compiler keeps in registers). pl rows i-disjoint per pair
// (direct store to shared pl_s[k]); pcol per-wave slices merged pairwise.
// Pad correction: pl-=11, pr-=11, Z = sum(pl_raw[:197]) - 197*11.
// NOTE: no min-waves launch bound (v6's (512,4) forced VGPR=64 -> spill).
// ---------------------------------------------------------------------------
__global__ __launch_bounds__(512) void tritt_k(
    const float* __restrict__ abcde, float* __restrict__ z)
{
    __shared__ __align__(16) unsigned short a_lds[TP * 64];
    __shared__ __align__(16) unsigned short b_lds[TP * 64];
    __shared__ float pl_s[4][TP];
    __shared__ float pr_s[8][TP];
    __shared__ float zp[8][DH_];

    int tid = threadIdx.x, lane = tid & 63, wv = tid >> 6;   // wv 0..7
    int k = wv >> 1;          // q slot (0..3)
    int wh = wv & 1;          // i-half
    int bh = blockIdx.y;
    int b = bh >> 2, h = bh & 3;
    const float* base = abcde + (long)b * TT * ABCDE_N;
    const float SC = 1.4426950408889634f / 64.f;   // log2(e)/DH
    int q = blockIdx.x * 4 + k;
    bool qok = (q < TT);

    // stage A and B once (bf16, swizzled), 512 threads
    for (int i = tid; i < TP * 8; i += 512) {
        int row = i >> 3, ch = i & 7;
        int idx = row * 64 + ((ch * 8) ^ ((row & 7) << 3));
        unsigned short av[8], bv[8];
        if (row < TT) {
            const float* srcA = base + (long)row * ABCDE_N + h * 64 + ch * 8;
            const float* srcB = srcA + 256;
            float4 a0 = *(const float4*)(srcA);
            float4 a1 = *(const float4*)(srcA + 4);
            float4 b0 = *(const float4*)(srcB);
            float4 b1 = *(const float4*)(srcB + 4);
            av[0] = f2bf(a0.x); av[1] = f2bf(a0.y); av[2] = f2bf(a0.z); av[3] = f2bf(a0.w);
            av[4] = f2bf(a1.x); av[5] = f2bf(a1.y); av[6] = f2bf(a1.z); av[7] = f2bf(a1.w);
            bv[0] = f2bf(b0.x); bv[1] = f2bf(b0.y); bv[2] = f2bf(b0.z); bv[3] = f2bf(b0.w);
            bv[4] = f2bf(b1.x); bv[5] = f2bf(b1.y); bv[6] = f2bf(b1.z); bv[7] = f2bf(b1.w);
        } else {
#pragma unroll
            for (int j = 0; j < 8; j++) { av[j] = 0; bv[j] = 0; }
        }
        *(short8_t*)&a_lds[idx] = *(const short8_t*)av;
        *(short8_t*)&b_lds[idx] = *(const short8_t*)bv;
    }
    __syncthreads();

    int lm = lane & 15;
    int lg = lane >> 4;

    // c_q fragments in registers (SC folded)
    const float* cp = base + (long)(qok ? q : 0) * ABCDE_N + 512 + h * 64;
    float c0[8], c1[8];
    {
        float4 v0 = *(const float4*)(cp + lg * 8);
        float4 v1 = *(const float4*)(cp + lg * 8 + 4);
        float4 v2 = *(const float4*)(cp + (lg + 4) * 8);
        float4 v3 = *(const float4*)(cp + (lg + 4) * 8 + 4);
        c0[0] = v0.x * SC; c0[1] = v0.y * SC; c0[2] = v0.z * SC; c0[3] = v0.w * SC;
        c0[4] = v1.x * SC; c0[5] = v1.y * SC; c0[6] = v1.z * SC; c0[7] = v1.w * SC;
        c1[0] = v2.x * SC; c1[1] = v2.y * SC; c1[2] = v2.z * SC; c1[3] = v2.w * SC;
        c1[4] = v3.x * SC; c1[5] = v3.y * SC; c1[6] = v3.z * SC; c1[7] = v3.w * SC;
    }

    // hoist ALL B fragments — static loop, identical to v3 (compiler keeps in regs)
    short8_t bf0[NT16], bf1[NT16];
#pragma unroll
    for (int j = 0; j < NT16; j++) {
        int brow = j * 16 + lm;
        bf0[j] = *(const short8_t*)&b_lds[brow * 64 + (((lg    ) * 8) ^ ((brow & 7) << 3))];
        bf1[j] = *(const short8_t*)&b_lds[brow * 64 + (((lg + 4) * 8) ^ ((brow & 7) << 3))];
    }

    float pcol[NT16];
#pragma unroll
    for (int j = 0; j < NT16; j++) pcol[j] = 0.f;

    if (qok) {
#pragma unroll 1
        for (int i = wh; i < NT16; i += 2) {
            int arow = i * 16 + lm;
            short8_t af0 = *(const short8_t*)&a_lds[arow * 64 + (((lg    ) * 8) ^ ((arow & 7) << 3))];
            short8_t af1 = *(const short8_t*)&a_lds[arow * 64 + (((lg + 4) * 8) ^ ((arow & 7) << 3))];
            short8_t ac0, ac1;
#pragma unroll
            for (int e = 0; e < 8; e++) {
                ac0[e] = (short)f2bf(bf2f((unsigned short)af0[e]) * c0[e]);
                ac1[e] = (short)f2bf(bf2f((unsigned short)af1[e]) * c1[e]);
            }
            float prow[4] = {0.f, 0.f, 0.f, 0.f};
#pragma unroll
            for (int j = 0; j < NT16; j++) {
                f32x4 acc = {0.f, 0.f, 0.f, 0.f};
                acc = __builtin_amdgcn_mfma_f32_16x16x32_bf16(ac0, bf0[j], acc, 0, 0, 0);
                acc = __builtin_amdgcn_mfma_f32_16x16x32_bf16(ac1, bf1[j], acc, 0, 0, 0);
                float e0 = __builtin_amdgcn_exp2f(acc[0]);
                float e1 = __builtin_amdgcn_exp2f(acc[1]);
                float e2 = __builtin_amdgcn_exp2f(acc[2]);
                float e3 = __builtin_amdgcn_exp2f(acc[3]);
                prow[0] += e0; prow[1] += e1; prow[2] += e2; prow[3] += e3;
                pcol[j] += (e0 + e1) + (e2 + e3);
            }
#pragma unroll
            for (int r = 0; r < 4; r++) {
                prow[r] += __shfl_xor(prow[r], 1, 64);
                prow[r] += __shfl_xor(prow[r], 2, 64);
                prow[r] += __shfl_xor(prow[r], 4, 64);
                prow[r] += __shfl_xor(prow[r], 8, 64);
            }
            if (lm == 0) {
                int rb = i * 16 + lg * 4;
#pragma unroll
                for (int r = 0; r < 4; r++) pl_s[k][rb + r] = prow[r];   // i-disjoint across pair
            }
        }
    }
    // column marginal slices per wave (zeros if !qok)
#pragma unroll
    for (int j = 0; j < NT16; j++) {
        float c = pcol[j];
        c += __shfl_xor(c, 16, 64);
        c += __shfl_xor(c, 32, 64);
        if (lane < 16) pr_s[wv][j * 16 + lane] = c;
    }
    __syncthreads();

    // merge pr pair slices: pr_s[2k] += pr_s[2k+1]
    for (int idx = tid; idx < 4 * TP; idx += 512) {
        int kk = idx / TP, s = idx - kk * TP;
        pr_s[2 * kk][s] += pr_s[2 * kk + 1][s];
    }
    __syncthreads();

    if (qok) {
        // Z (pad-corrected), computed redundantly by both waves of the pair
        float zpart = 0.f;
        for (int s = lane; s < TT; s += 64) zpart += pl_s[k][s];
        zpart = waveReduceSum(zpart);
        float rz = 1.f / (zpart - 11.f * TT);

        // epilogue: pair waves split s odd/even
        const float* dp = base + 768 + h * 64 + lane;
        const float* ep = base + 1024 + h * 64 + lane;
        float zacc = 0.f;
        for (int s = wh; s < TT; s += 2) {
            zacc = fmaf(pl_s[k][s] - 11.f, dp[(long)s * ABCDE_N], zacc);
            zacc = fmaf(pr_s[2 * k][s] - 11.f, ep[(long)s * ABCDE_N], zacc);
        }
        zp[wv][lane] = zacc * rz;
    }
    __syncthreads();

    if (tid < 256) {
        int kk = tid >> 6, d = tid & 63;
        int qw = blockIdx.x * 4 + kk;
        if (qw < TT) {
            z[((long)b * TT + qw) * DIMM + h * 64 + d] = zp[2 * kk][d] + zp[2 * kk + 1][d];
        }
    }
}

// ---------------------------------------------------------------------------
extern "C" void kernel_launch(void* const* d_in, const int* in_sizes, int n_in,
                              void* d_out, int out_size, void* d_ws, size_t ws_size,
                              hipStream_t stream)
{
    const float* img    = (const float*)d_in[0];
    const float* g1     = (const float*)d_in[1];
    const float* b1     = (const float*)d_in[2];
    const float* pw     = (const float*)d_in[3];
    const float* pb     = (const float*)d_in[4];
    const float* g2     = (const float*)d_in[5];
    const float* b2     = (const float*)d_in[6];
    const float* pos    = (const float*)d_in[7];
    const float* cls    = (const float*)d_in[8];
    const float* attn_g = (const float*)d_in[9];
    const float* attn_b = (const float*)d_in[10];
    const float* w_abc  = (const float*)d_in[11];
    const float* b_abc  = (const float*)d_in[12];
    const float* w_out  = (const float*)d_in[13];
    const float* b_out  = (const float*)d_in[14];
    const float* ff_g   = (const float*)d_in[15];
    const float* ff_b   = (const float*)d_in[16];
    const float* w1     = (const float*)d_in[17];
    const float* b1f    = (const float*)d_in[18];
    const float* w2     = (const float*)d_in[19];
    const float* b2f    = (const float*)d_in[20];
    const float* fin_g  = (const float*)d_in[21];
    const float* fin_b  = (const float*)d_in[22];
    const float* hw     = (const float*)d_in[23];
    const float* hb     = (const float*)d_in[24];
    float* out = (float*)d_out;

    const int MROWS = BB * TT;  // 394
    float* ws = (float*)d_ws;
    float* xa = ws;                       // [394,256]
    float* xb = xa + (long)MROWS * DIMM;  // [394,256]
    float* zb = xb + (long)MROWS * DIMM;  // [394,256]
    float* ab = zb + (long)MROWS * DIMM;  // [394,1280] (also reused as [394,1024] h)

    patch_embed_k<<<99, 256, 0, stream>>>(img, g1, b1, pw, pb, g2, b2, pos, cls, xa);

    const int GY = (MROWS + 3) / 4;         // 99
    const int QT4 = (TT + 3) / 4;           // 50
    for (int i = 0; i < 2; i++) {
        gemm_ksplit_k<<<dim3(ABCDE_N / 64, GY), 512, 0, stream>>>(
            xa, DIMM, MROWS, DIMM, ABCDE_N,
            w_abc + (long)i * DIMM * ABCDE_N, b_abc + (long)i * ABCDE_N,
            nullptr, ab, attn_g + i * DIMM, attn_b + i * DIMM, 0);
        tritt_k<<<dim3(QT4, BB * HEADS_), 512, 0, stream>>>(ab, zb);
        gemm_ksplit_k<<<dim3(DIMM / 64, GY), 512, 0, stream>>>(
            zb, DIMM, MROWS, DIMM, DIMM,
            w_out + (long)i * DIMM * DIMM, b_out + (long)i * DIMM,
            xa, xb, nullptr, nullptr, 0);
        gemm_ksplit_k<<<dim3(MLP_ / 64, GY), 512, 0, stream>>>(
            xb, DIMM, MROWS, DIMM, MLP_,
            w1 + (long)i * DIMM * MLP_, b1f + (long)i * MLP_,
            nullptr, ab, ff_g + i * DIMM, ff_b + i * DIMM, 1);
        gemm_ksplit_k<<<dim3(DIMM / 64, GY), 512, 0, stream>>>(
            ab, MLP_, MROWS, MLP_, DIMM,
            w2 + (long)i * MLP_ * DIMM, b2f + (long)i * DIMM,
            xb, xa, nullptr, nullptr, 0);
    }
    gemm_ksplit_k<<<dim3((NCLS_ + 63) / 64, 1), 512, 0, stream>>>(
        xa, (long)TT * DIMM, BB, DIMM, NCLS_,
        hw, hb, nullptr, out, fin_g, fin_b, 0);
}

// Round 14
// 223.730 us; speedup vs baseline: 1.3125x; 1.3125x over previous
//
#include <hip/hip_runtime.h>
#include <hip/hip_bf16.h>

// Dims
#define BB 2
#define TT 197
#define TP 208          // padded T (13*16)
#define NT16 13
#define DIMM 256
#define HEADS_ 4
#define DH_ 64
#define ABCDE_N 1280   // 5*HEADS*DH = 5*256
#define MLP_ 1024
#define NCLS_ 1000
#define PATCH_DIM_ 768

typedef __attribute__((ext_vector_type(8))) short short8_t;   // 8 bf16
typedef __attribute__((ext_vector_type(4))) float f32x4;

__device__ __forceinline__ float waveReduceSum(float v) {
#pragma unroll
    for (int off = 32; off > 0; off >>= 1) v += __shfl_xor(v, off, 64);
    return v;
}

// sum over the 16-lane row via DPP row_ror (no LDS, replaces ds_bpermute tree)
__device__ __forceinline__ float rowReduceSum16(float v) {
    // row_ror:N ctrl = 0x120 | N ; rotate-reduce over a 16-lane DPP row
    v += __uint_as_float(__builtin_amdgcn_update_dpp(
            0, __float_as_uint(v), 0x121, 0xF, 0xF, true));
    v += __uint_as_float(__builtin_amdgcn_update_dpp(
            0, __float_as_uint(v), 0x122, 0xF, 0xF, true));
    v += __uint_as_float(__builtin_amdgcn_update_dpp(
            0, __float_as_uint(v), 0x124, 0xF, 0xF, true));
    v += __uint_as_float(__builtin_amdgcn_update_dpp(
            0, __float_as_uint(v), 0x128, 0xF, 0xF, true));
    return v;
}

__device__ __forceinline__ unsigned short f2bf(float x) {
    unsigned int u = __float_as_uint(x);
    u += 0x7FFFu + ((u >> 16) & 1u);   // RNE
    return (unsigned short)(u >> 16);
}

__device__ __forceinline__ float bf2f(unsigned short u) {
    return __uint_as_float(((unsigned int)u) << 16);
}

// ---------------------------------------------------------------------------
// Patch embed (unchanged)
// ---------------------------------------------------------------------------
__global__ __launch_bounds__(256) void patch_embed_k(
    const float* __restrict__ img, const float* __restrict__ g1, const float* __restrict__ b1,
    const float* __restrict__ pw, const float* __restrict__ pb,
    const float* __restrict__ g2, const float* __restrict__ b2,
    const float* __restrict__ pos, const float* __restrict__ cls,
    float* __restrict__ xa)
{
    int tid = threadIdx.x;
    if (blockIdx.x == 98) {
        for (int b = 0; b < BB; b++)
            xa[(long)b * TT * DIMM + tid] = cls[tid] + pos[tid];
        return;
    }
    __shared__ __align__(16) float xs[4][PATCH_DIM_];
    __shared__ float red[8];
    int pr0 = blockIdx.x * 4;
    for (int r = 0; r < 4; r++) {
        int pr = pr0 + r;
        int b = pr / 196, patch = pr % 196;
        int gh = patch / 14, gw = patch % 14;
        for (int j = tid; j < PATCH_DIM_; j += 256) {
            int c = j % 3, p2 = (j / 3) % 16, p1 = j / 48;
            xs[r][j] = img[(((long)b * 3 + c) * 224 + gh * 16 + p1) * 224 + gw * 16 + p2];
        }
    }
    __syncthreads();
    int wv = tid >> 6, lane = tid & 63;
    {
        int r = wv;
        float s = 0.f, s2 = 0.f;
        for (int j = lane; j < PATCH_DIM_; j += 64) { float v = xs[r][j]; s += v; s2 += v * v; }
        s = waveReduceSum(s); s2 = waveReduceSum(s2);
        float m = s / PATCH_DIM_;
        float rs = rsqrtf(s2 / PATCH_DIM_ - m * m + 1e-5f);
        for (int j = lane; j < PATCH_DIM_; j += 64)
            xs[r][j] = (xs[r][j] - m) * rs * g1[j] + b1[j];
    }
    __syncthreads();
    float acc[4] = {0.f, 0.f, 0.f, 0.f};
    for (int k = 0; k < PATCH_DIM_; k += 4) {
        float w0 = pw[(k + 0) * DIMM + tid];
        float w1 = pw[(k + 1) * DIMM + tid];
        float w2 = pw[(k + 2) * DIMM + tid];
        float w3 = pw[(k + 3) * DIMM + tid];
#pragma unroll
        for (int r = 0; r < 4; r++) {
            float4 xv = *(const float4*)&xs[r][k];
            acc[r] = fmaf(xv.x, w0, fmaf(xv.y, w1, fmaf(xv.z, w2, fmaf(xv.w, w3, acc[r]))));
        }
    }
#pragma unroll
    for (int r = 0; r < 4; r++) acc[r] += pb[tid];
    for (int r = 0; r < 4; r++) {
        float s = waveReduceSum(acc[r]);
        float s2 = waveReduceSum(acc[r] * acc[r]);
        if (lane == 0) { red[wv * 2] = s; red[wv * 2 + 1] = s2; }
        __syncthreads();
        float S = red[0] + red[2] + red[4] + red[6];
        float S2 = red[1] + red[3] + red[5] + red[7];
        __syncthreads();
        float m = S / DIMM;
        float rs = rsqrtf(S2 / DIMM - m * m + 1e-5f);
        int pr = pr0 + r;
        int b = pr / 196, patch = pr % 196;
        float v = (acc[r] - m) * rs * g2[tid] + b2[tid] + pos[(1 + patch) * DIMM + tid];
        xa[((long)b * TT + 1 + patch) * DIMM + tid] = v;
    }
}

// ---------------------------------------------------------------------------
// K-split GEMM v2 (unchanged from round 12): 512 threads, 8-way K-split.
// ---------------------------------------------------------------------------
__global__ __launch_bounds__(512) void gemm_ksplit_k(
    const float* __restrict__ x, long x_stride, int M, int K, int N,
    const float* __restrict__ w, const float* __restrict__ bias,
    const float* __restrict__ res, float* __restrict__ out,
    const float* __restrict__ ln_g, const float* __restrict__ ln_b,
    int do_gelu)
{
    __shared__ __align__(16) float xs[4 * 1024];
    __shared__ float psum[8 * 4 * 64];   // [wave][row][col]
    int tid = threadIdx.x, lane = tid & 63, wv = tid >> 6;   // wv 0..7
    int row0 = blockIdx.y * 4, col0 = blockIdx.x * 64;

    for (int i = tid; i < 4 * K; i += 512) {
        int r = i / K, k = i - r * K;
        int row = row0 + r;
        xs[i] = (row < M) ? x[(long)row * x_stride + k] : 0.f;
    }
    __syncthreads();
    if (ln_g) {
        if (wv < 4) {   // one wave per row
            float* xr = xs + wv * K;
            float s = 0.f, s2 = 0.f;
            for (int k = lane; k < K; k += 64) { float v = xr[k]; s += v; s2 += v * v; }
            s = waveReduceSum(s); s2 = waveReduceSum(s2);
            float m = s / K;
            float rs = rsqrtf(s2 / K - m * m + 1e-5f);
            for (int k = lane; k < K; k += 64)
                xr[k] = (xr[k] - m) * rs * ln_g[k] + ln_b[k];
        }
        __syncthreads();
    }

    int col = col0 + lane;
    float a0 = 0.f, a1 = 0.f, a2 = 0.f, a3 = 0.f;
    int kq = K >> 3;
    if (col < N) {
        const float* x0 = xs + wv * kq;
        const float* x1 = x0 + K;
        const float* x2 = x1 + K;
        const float* x3 = x2 + K;
        const float* wp = w + (long)(wv * kq) * N + col;
        long nl = N;
        for (int kk = 0; kk < kq; kk += 4) {
            float w0 = wp[0], w1 = wp[nl], w2 = wp[2 * nl], w3 = wp[3 * nl];
            wp += 4 * nl;
            float4 v0 = *(const float4*)(x0 + kk);
            float4 v1 = *(const float4*)(x1 + kk);
            float4 v2 = *(const float4*)(x2 + kk);
            float4 v3 = *(const float4*)(x3 + kk);
            a0 = fmaf(v0.x, w0, fmaf(v0.y, w1, fmaf(v0.z, w2, fmaf(v0.w, w3, a0))));
            a1 = fmaf(v1.x, w0, fmaf(v1.y, w1, fmaf(v1.z, w2, fmaf(v1.w, w3, a1))));
            a2 = fmaf(v2.x, w0, fmaf(v2.y, w1, fmaf(v2.z, w2, fmaf(v2.w, w3, a2))));
            a3 = fmaf(v3.x, w0, fmaf(v3.y, w1, fmaf(v3.z, w2, fmaf(v3.w, w3, a3))));
        }
    }
    psum[wv * 256 + 0 * 64 + lane] = a0;
    psum[wv * 256 + 1 * 64 + lane] = a1;
    psum[wv * 256 + 2 * 64 + lane] = a2;
    psum[wv * 256 + 3 * 64 + lane] = a3;
    __syncthreads();

    if (tid < 256) {
        int r = tid >> 6, c = tid & 63;
        float v = ((psum[r * 64 + c]        + psum[256 + r * 64 + c])
                +  (psum[512 + r * 64 + c]  + psum[768 + r * 64 + c]))
                + ((psum[1024 + r * 64 + c] + psum[1280 + r * 64 + c])
                +  (psum[1536 + r * 64 + c] + psum[1792 + r * 64 + c]));
        int row = row0 + r, cw = col0 + c;
        if (row < M && cw < N) {
            if (bias) v += bias[cw];
            if (do_gelu) v = 0.5f * v * (1.f + erff(v * 0.70710678118654752f));
            if (res) v += res[(long)row * N + cw];
            out[(long)row * N + cw] = v;
        }
    }
}

// ---------------------------------------------------------------------------
// Trittention v3-DPP: exact round-12 v3 structure, with the per-i prow
// reduction tree switched from __shfl_xor (ds_bpermute, ~120cyc LDS latency,
// 4-deep x13 per wave) to DPP row_ror rotate-reduce (pure VALU). Epilogue
// FMA chains split 4-way. Everything else byte-identical.
// ---------------------------------------------------------------------------
__global__ __launch_bounds__(256) void tritt_k(
    const float* __restrict__ abcde, float* __restrict__ z)
{
    __shared__ __align__(16) unsigned short a_lds[TP * 64];
    __shared__ __align__(16) unsigned short b_lds[TP * 64];
    __shared__ float pl_s[4][TP];
    __shared__ float pr_s[4][TP];

    int tid = threadIdx.x, lane = tid & 63, wv = tid >> 6;
    int bh = blockIdx.y;
    int b = bh >> 2, h = bh & 3;
    const float* base = abcde + (long)b * TT * ABCDE_N;
    const float SC = 1.4426950408889634f / 64.f;   // log2(e)/DH

    // stage A and B once (bf16, swizzled)
    for (int i = tid; i < TP * 8; i += 256) {
        int row = i >> 3, ch = i & 7;
        int idx = row * 64 + ((ch * 8) ^ ((row & 7) << 3));
        unsigned short av[8], bv[8];
        if (row < TT) {
            const float* srcA = base + (long)row * ABCDE_N + h * 64 + ch * 8;
            const float* srcB = srcA + 256;
            float4 a0 = *(const float4*)(srcA);
            float4 a1 = *(const float4*)(srcA + 4);
            float4 b0 = *(const float4*)(srcB);
            float4 b1 = *(const float4*)(srcB + 4);
            av[0] = f2bf(a0.x); av[1] = f2bf(a0.y); av[2] = f2bf(a0.z); av[3] = f2bf(a0.w);
            av[4] = f2bf(a1.x); av[5] = f2bf(a1.y); av[6] = f2bf(a1.z); av[7] = f2bf(a1.w);
            bv[0] = f2bf(b0.x); bv[1] = f2bf(b0.y); bv[2] = f2bf(b0.z); bv[3] = f2bf(b0.w);
            bv[4] = f2bf(b1.x); bv[5] = f2bf(b1.y); bv[6] = f2bf(b1.z); bv[7] = f2bf(b1.w);
        } else {
#pragma unroll
            for (int j = 0; j < 8; j++) { av[j] = 0; bv[j] = 0; }
        }
        *(short8_t*)&a_lds[idx] = *(const short8_t*)av;
        *(short8_t*)&b_lds[idx] = *(const short8_t*)bv;
    }
    __syncthreads();

    int q = blockIdx.x * 4 + wv;
    if (q >= TT) return;

    int lm = lane & 15;
    int lg = lane >> 4;

    // c_q fragments in registers (SC folded)
    const float* cp = base + (long)q * ABCDE_N + 512 + h * 64;
    float c0[8], c1[8];
    {
        float4 v0 = *(const float4*)(cp + lg * 8);
        float4 v1 = *(const float4*)(cp + lg * 8 + 4);
        float4 v2 = *(const float4*)(cp + (lg + 4) * 8);
        float4 v3 = *(const float4*)(cp + (lg + 4) * 8 + 4);
        c0[0] = v0.x * SC; c0[1] = v0.y * SC; c0[2] = v0.z * SC; c0[3] = v0.w * SC;
        c0[4] = v1.x * SC; c0[5] = v1.y * SC; c0[6] = v1.z * SC; c0[7] = v1.w * SC;
        c1[0] = v2.x * SC; c1[1] = v2.y * SC; c1[2] = v2.z * SC; c1[3] = v2.w * SC;
        c1[4] = v3.x * SC; c1[5] = v3.y * SC; c1[6] = v3.z * SC; c1[7] = v3.w * SC;
    }

    // hoist all B fragments (26 x short8)
    short8_t bf0[NT16], bf1[NT16];
#pragma unroll
    for (int j = 0; j < NT16; j++) {
        int brow = j * 16 + lm;
        bf0[j] = *(const short8_t*)&b_lds[brow * 64 + (((lg    ) * 8) ^ ((brow & 7) << 3))];
        bf1[j] = *(const short8_t*)&b_lds[brow * 64 + (((lg + 4) * 8) ^ ((brow & 7) << 3))];
    }

    float pcol[NT16];
#pragma unroll
    for (int j = 0; j < NT16; j++) pcol[j] = 0.f;

#pragma unroll 1
    for (int i = 0; i < NT16; i++) {
        int arow = i * 16 + lm;
        short8_t af0 = *(const short8_t*)&a_lds[arow * 64 + (((lg    ) * 8) ^ ((arow & 7) << 3))];
        short8_t af1 = *(const short8_t*)&a_lds[arow * 64 + (((lg + 4) * 8) ^ ((arow & 7) << 3))];
        short8_t ac0, ac1;
#pragma unroll
        for (int e = 0; e < 8; e++) {
            ac0[e] = (short)f2bf(bf2f((unsigned short)af0[e]) * c0[e]);
            ac1[e] = (short)f2bf(bf2f((unsigned short)af1[e]) * c1[e]);
        }
        float prow[4] = {0.f, 0.f, 0.f, 0.f};
#pragma unroll
        for (int j = 0; j < NT16; j++) {
            f32x4 acc = {0.f, 0.f, 0.f, 0.f};
            acc = __builtin_amdgcn_mfma_f32_16x16x32_bf16(ac0, bf0[j], acc, 0, 0, 0);
            acc = __builtin_amdgcn_mfma_f32_16x16x32_bf16(ac1, bf1[j], acc, 0, 0, 0);
            float e0 = __builtin_amdgcn_exp2f(acc[0]);
            float e1 = __builtin_amdgcn_exp2f(acc[1]);
            float e2 = __builtin_amdgcn_exp2f(acc[2]);
            float e3 = __builtin_amdgcn_exp2f(acc[3]);
            prow[0] += e0; prow[1] += e1; prow[2] += e2; prow[3] += e3;
            pcol[j] += (e0 + e1) + (e2 + e3);
        }
        // row sums over the 16 column-lanes: DPP rotate-reduce (no LDS)
#pragma unroll
        for (int r = 0; r < 4; r++) prow[r] = rowReduceSum16(prow[r]);
        if (lm == 0) {
            int rb = i * 16 + lg * 4;
#pragma unroll
            for (int r = 0; r < 4; r++) pl_s[wv][rb + r] = prow[r];
        }
    }
    // column marginals: reduce over k-groups (xor 16/32 cross-row, keep shfl)
#pragma unroll
    for (int j = 0; j < NT16; j++) {
        float c = pcol[j];
        c += __shfl_xor(c, 16, 64);
        c += __shfl_xor(c, 32, 64);
        if (lane < 16) pr_s[wv][j * 16 + lane] = c;
    }

    // Z (wave-local)
    float zpart = 0.f;
    for (int s = lane; s < TT; s += 64) zpart += pl_s[wv][s];
    zpart = waveReduceSum(zpart);
    float rz = 1.f / (zpart - 11.f * TT);

    // z = (pl_true @ d + pr_true @ e) * rz   (lane = dh), 4 FMA chains
    const float* dp = base + 768 + h * 64 + lane;
    const float* ep = base + 1024 + h * 64 + lane;
    float z0 = 0.f, z1 = 0.f, z2 = 0.f, z3 = 0.f;
    int s = 0;
    for (; s + 1 < TT; s += 2) {
        z0 = fmaf(pl_s[wv][s]     - 11.f, dp[(long)s * ABCDE_N],       z0);
        z1 = fmaf(pr_s[wv][s]     - 11.f, ep[(long)s * ABCDE_N],       z1);
        z2 = fmaf(pl_s[wv][s + 1] - 11.f, dp[(long)(s + 1) * ABCDE_N], z2);
        z3 = fmaf(pr_s[wv][s + 1] - 11.f, ep[(long)(s + 1) * ABCDE_N], z3);
    }
    z0 = fmaf(pl_s[wv][s] - 11.f, dp[(long)s * ABCDE_N], z0);   // s = 196
    z1 = fmaf(pr_s[wv][s] - 11.f, ep[(long)s * ABCDE_N], z1);
    z[((long)b * TT + q) * DIMM + h * 64 + lane] = ((z0 + z1) + (z2 + z3)) * rz;
}

// ---------------------------------------------------------------------------
extern "C" void kernel_launch(void* const* d_in, const int* in_sizes, int n_in,
                              void* d_out, int out_size, void* d_ws, size_t ws_size,
                              hipStream_t stream)
{
    const float* img    = (const float*)d_in[0];
    const float* g1     = (const float*)d_in[1];
    const float* b1     = (const float*)d_in[2];
    const float* pw     = (const float*)d_in[3];
    const float* pb     = (const float*)d_in[4];
    const float* g2     = (const float*)d_in[5];
    const float* b2     = (const float*)d_in[6];
    const float* pos    = (const float*)d_in[7];
    const float* cls    = (const float*)d_in[8];
    const float* attn_g = (const float*)d_in[9];
    const float* attn_b = (const float*)d_in[10];
    const float* w_abc  = (const float*)d_in[11];
    const float* b_abc  = (const float*)d_in[12];
    const float* w_out  = (const float*)d_in[13];
    const float* b_out  = (const float*)d_in[14];
    const float* ff_g   = (const float*)d_in[15];
    const float* ff_b   = (const float*)d_in[16];
    const float* w1     = (const float*)d_in[17];
    const float* b1f    = (const float*)d_in[18];
    const float* w2     = (const float*)d_in[19];
    const float* b2f    = (const float*)d_in[20];
    const float* fin_g  = (const float*)d_in[21];
    const float* fin_b  = (const float*)d_in[22];
    const float* hw     = (const float*)d_in[23];
    const float* hb     = (const float*)d_in[24];
    float* out = (float*)d_out;

    const int MROWS = BB * TT;  // 394
    float* ws = (float*)d_ws;
    float* xa = ws;                       // [394,256]
    float* xb = xa + (long)MROWS * DIMM;  // [394,256]
    float* zb = xb + (long)MROWS * DIMM;  // [394,256]
    float* ab = zb + (long)MROWS * DIMM;  // [394,1280] (also reused as [394,1024] h)

    patch_embed_k<<<99, 256, 0, stream>>>(img, g1, b1, pw, pb, g2, b2, pos, cls, xa);

    const int GY = (MROWS + 3) / 4;         // 99
    const int QT4 = (TT + 3) / 4;           // 50
    for (int i = 0; i < 2; i++) {
        gemm_ksplit_k<<<dim3(ABCDE_N / 64, GY), 512, 0, stream>>>(
            xa, DIMM, MROWS, DIMM, ABCDE_N,
            w_abc + (long)i * DIMM * ABCDE_N, b_abc + (long)i * ABCDE_N,
            nullptr, ab, attn_g + i * DIMM, attn_b + i * DIMM, 0);
        tritt_k<<<dim3(QT4, BB * HEADS_), 256, 0, stream>>>(ab, zb);
        gemm_ksplit_k<<<dim3(DIMM / 64, GY), 512, 0, stream>>>(
            zb, DIMM, MROWS, DIMM, DIMM,
            w_out + (long)i * DIMM * DIMM, b_out + (long)i * DIMM,
            xa, xb, nullptr, nullptr, 0);
        gemm_ksplit_k<<<dim3(MLP_ / 64, GY), 512, 0, stream>>>(
            xb, DIMM, MROWS, DIMM, MLP_,
            w1 + (long)i * DIMM * MLP_, b1f + (long)i * MLP_,
            nullptr, ab, ff_g + i * DIMM, ff_b + i * DIMM, 1);
        gemm_ksplit_k<<<dim3(DIMM / 64, GY), 512, 0, stream>>>(
            ab, MLP_, MROWS, MLP_, DIMM,
            w2 + (long)i * MLP_ * DIMM, b2f + (long)i * DIMM,
            xb, xa, nullptr, nullptr, 0);
    }
    gemm_ksplit_k<<<dim3((NCLS_ + 63) / 64, 1), 512, 0, stream>>>(
        xa, (long)TT * DIMM, BB, DIMM, NCLS_,
        hw, hb, nullptr, out, fin_g, fin_b, 0);
}

// Round 15
// 211.198 us; speedup vs baseline: 1.3904x; 1.0593x over previous
//
#include <hip/hip_runtime.h>
#include <hip/hip_bf16.h>

// Dims
#define BB 2
#define TT 197
#define TP 208          // padded T (13*16)
#define NT16 13
#define DIMM 256
#define HEADS_ 4
#define DH_ 64
#define ABCDE_N 1280   // 5*HEADS*DH = 5*256
#define MLP_ 1024
#define NCLS_ 1000
#define PATCH_DIM_ 768

typedef __attribute__((ext_vector_type(8))) short short8_t;   // 8 bf16
typedef __attribute__((ext_vector_type(4))) float f32x4;

__device__ __forceinline__ float waveReduceSum(float v) {
#pragma unroll
    for (int off = 32; off > 0; off >>= 1) v += __shfl_xor(v, off, 64);
    return v;
}

// sum over the 16-lane row via DPP row_ror (no LDS)
__device__ __forceinline__ float rowReduceSum16(float v) {
    v += __uint_as_float(__builtin_amdgcn_update_dpp(
            0, __float_as_uint(v), 0x121, 0xF, 0xF, true));
    v += __uint_as_float(__builtin_amdgcn_update_dpp(
            0, __float_as_uint(v), 0x122, 0xF, 0xF, true));
    v += __uint_as_float(__builtin_amdgcn_update_dpp(
            0, __float_as_uint(v), 0x124, 0xF, 0xF, true));
    v += __uint_as_float(__builtin_amdgcn_update_dpp(
            0, __float_as_uint(v), 0x128, 0xF, 0xF, true));
    return v;
}

__device__ __forceinline__ unsigned short f2bf(float x) {
    unsigned int u = __float_as_uint(x);
    u += 0x7FFFu + ((u >> 16) & 1u);   // RNE
    return (unsigned short)(u >> 16);
}

__device__ __forceinline__ float bf2f(unsigned short u) {
    return __uint_as_float(((unsigned int)u) << 16);
}

// ---------------------------------------------------------------------------
// Patch embed v2: 1024 threads, K=768 split 4-ways (ks = tid>>8, 192 each),
// psum LDS reduce. Same grid (99): blocks 0..97 = 4 patch rows, 98 = cls.
// Fixes the 1-wave/SIMD serial-K latency of v1.
// ---------------------------------------------------------------------------
__global__ __launch_bounds__(1024) void patch_embed_k(
    const float* __restrict__ img, const float* __restrict__ g1, const float* __restrict__ b1,
    const float* __restrict__ pw, const float* __restrict__ pb,
    const float* __restrict__ g2, const float* __restrict__ b2,
    const float* __restrict__ pos, const float* __restrict__ cls,
    float* __restrict__ xa)
{
    int tid = threadIdx.x;
    if (blockIdx.x == 98) {
        if (tid < DIMM)
            for (int b = 0; b < BB; b++)
                xa[(long)b * TT * DIMM + tid] = cls[tid] + pos[tid];
        return;
    }
    __shared__ __align__(16) float xs[4][PATCH_DIM_];
    __shared__ float psum[4][4][DIMM];   // [ks][row][col]
    __shared__ float red[8];
    int pr0 = blockIdx.x * 4;
    int wv16 = tid >> 6, lane = tid & 63;

    // gather 4 patch rows (1024 threads)
    for (int i = tid; i < 4 * PATCH_DIM_; i += 1024) {
        int r = i / PATCH_DIM_, j = i - r * PATCH_DIM_;
        int pr = pr0 + r;
        int b = pr / 196, patch = pr % 196;
        int gh = patch / 14, gw = patch % 14;
        int c = j % 3, p2 = (j / 3) % 16, p1 = j / 48;
        xs[r][j] = img[(((long)b * 3 + c) * 224 + gh * 16 + p1) * 224 + gw * 16 + p2];
    }
    __syncthreads();
    // LN1: waves 0..3, one per row
    if (wv16 < 4) {
        int r = wv16;
        float s = 0.f, s2 = 0.f;
        for (int j = lane; j < PATCH_DIM_; j += 64) { float v = xs[r][j]; s += v; s2 += v * v; }
        s = waveReduceSum(s); s2 = waveReduceSum(s2);
        float m = s / PATCH_DIM_;
        float rs = rsqrtf(s2 / PATCH_DIM_ - m * m + 1e-5f);
        for (int j = lane; j < PATCH_DIM_; j += 64)
            xs[r][j] = (xs[r][j] - m) * rs * g1[j] + b1[j];
    }
    __syncthreads();
    // GEMM: col = tid&255, K-quarter = tid>>8
    int col = tid & 255, ks = tid >> 8;
    int k0 = ks * (PATCH_DIM_ / 4);
    float acc[4] = {0.f, 0.f, 0.f, 0.f};
    for (int k = k0; k < k0 + PATCH_DIM_ / 4; k += 4) {
        float w0 = pw[(k + 0) * DIMM + col];
        float w1 = pw[(k + 1) * DIMM + col];
        float w2 = pw[(k + 2) * DIMM + col];
        float w3 = pw[(k + 3) * DIMM + col];
#pragma unroll
        for (int r = 0; r < 4; r++) {
            float4 xv = *(const float4*)&xs[r][k];
            acc[r] = fmaf(xv.x, w0, fmaf(xv.y, w1, fmaf(xv.z, w2, fmaf(xv.w, w3, acc[r]))));
        }
    }
#pragma unroll
    for (int r = 0; r < 4; r++) psum[ks][r][col] = acc[r];
    __syncthreads();

    float v4[4];
    if (tid < 256) {
#pragma unroll
        for (int r = 0; r < 4; r++)
            v4[r] = (psum[0][r][tid] + psum[1][r][tid])
                  + (psum[2][r][tid] + psum[3][r][tid]) + pb[tid];
    }
    // LN2 per row (block-reduce over 256 cols; waves 0..3), +pos, write
    for (int r = 0; r < 4; r++) {
        float s = 0.f, s2 = 0.f;
        if (tid < 256) {
            s = waveReduceSum(v4[r]);
            s2 = waveReduceSum(v4[r] * v4[r]);
            if (lane == 0) { red[wv16 * 2] = s; red[wv16 * 2 + 1] = s2; }
        }
        __syncthreads();
        float S = red[0] + red[2] + red[4] + red[6];
        float S2 = red[1] + red[3] + red[5] + red[7];
        __syncthreads();
        if (tid < 256) {
            float m = S / DIMM;
            float rs = rsqrtf(S2 / DIMM - m * m + 1e-5f);
            int pr = pr0 + r;
            int b = pr / 196, patch = pr % 196;
            float v = (v4[r] - m) * rs * g2[tid] + b2[tid] + pos[(1 + patch) * DIMM + tid];
            xa[((long)b * TT + 1 + patch) * DIMM + tid] = v;
        }
    }
}

// ---------------------------------------------------------------------------
// K-split GEMM v2 (unchanged): 512 threads, 8-way K-split.
// ---------------------------------------------------------------------------
__global__ __launch_bounds__(512) void gemm_ksplit_k(
    const float* __restrict__ x, long x_stride, int M, int K, int N,
    const float* __restrict__ w, const float* __restrict__ bias,
    const float* __restrict__ res, float* __restrict__ out,
    const float* __restrict__ ln_g, const float* __restrict__ ln_b,
    int do_gelu)
{
    __shared__ __align__(16) float xs[4 * 1024];
    __shared__ float psum[8 * 4 * 64];   // [wave][row][col]
    int tid = threadIdx.x, lane = tid & 63, wv = tid >> 6;   // wv 0..7
    int row0 = blockIdx.y * 4, col0 = blockIdx.x * 64;

    for (int i = tid; i < 4 * K; i += 512) {
        int r = i / K, k = i - r * K;
        int row = row0 + r;
        xs[i] = (row < M) ? x[(long)row * x_stride + k] : 0.f;
    }
    __syncthreads();
    if (ln_g) {
        if (wv < 4) {   // one wave per row
            float* xr = xs + wv * K;
            float s = 0.f, s2 = 0.f;
            for (int k = lane; k < K; k += 64) { float v = xr[k]; s += v; s2 += v * v; }
            s = waveReduceSum(s); s2 = waveReduceSum(s2);
            float m = s / K;
            float rs = rsqrtf(s2 / K - m * m + 1e-5f);
            for (int k = lane; k < K; k += 64)
                xr[k] = (xr[k] - m) * rs * ln_g[k] + ln_b[k];
        }
        __syncthreads();
    }

    int col = col0 + lane;
    float a0 = 0.f, a1 = 0.f, a2 = 0.f, a3 = 0.f;
    int kq = K >> 3;
    if (col < N) {
        const float* x0 = xs + wv * kq;
        const float* x1 = x0 + K;
        const float* x2 = x1 + K;
        const float* x3 = x2 + K;
        const float* wp = w + (long)(wv * kq) * N + col;
        long nl = N;
        for (int kk = 0; kk < kq; kk += 4) {
            float w0 = wp[0], w1 = wp[nl], w2 = wp[2 * nl], w3 = wp[3 * nl];
            wp += 4 * nl;
            float4 v0 = *(const float4*)(x0 + kk);
            float4 v1 = *(const float4*)(x1 + kk);
            float4 v2 = *(const float4*)(x2 + kk);
            float4 v3 = *(const float4*)(x3 + kk);
            a0 = fmaf(v0.x, w0, fmaf(v0.y, w1, fmaf(v0.z, w2, fmaf(v0.w, w3, a0))));
            a1 = fmaf(v1.x, w0, fmaf(v1.y, w1, fmaf(v1.z, w2, fmaf(v1.w, w3, a1))));
            a2 = fmaf(v2.x, w0, fmaf(v2.y, w1, fmaf(v2.z, w2, fmaf(v2.w, w3, a2))));
            a3 = fmaf(v3.x, w0, fmaf(v3.y, w1, fmaf(v3.z, w2, fmaf(v3.w, w3, a3))));
        }
    }
    psum[wv * 256 + 0 * 64 + lane] = a0;
    psum[wv * 256 + 1 * 64 + lane] = a1;
    psum[wv * 256 + 2 * 64 + lane] = a2;
    psum[wv * 256 + 3 * 64 + lane] = a3;
    __syncthreads();

    if (tid < 256) {
        int r = tid >> 6, c = tid & 63;
        float v = ((psum[r * 64 + c]        + psum[256 + r * 64 + c])
                +  (psum[512 + r * 64 + c]  + psum[768 + r * 64 + c]))
                + ((psum[1024 + r * 64 + c] + psum[1280 + r * 64 + c])
                +  (psum[1536 + r * 64 + c] + psum[1792 + r * 64 + c]));
        int row = row0 + r, cw = col0 + c;
        if (row < M && cw < N) {
            if (bias) v += bias[cw];
            if (do_gelu) v = 0.5f * v * (1.f + erff(v * 0.70710678118654752f));
            if (res) v += res[(long)row * N + cw];
            out[(long)row * N + cw] = v;
        }
    }
}

// ---------------------------------------------------------------------------
// Trittention v3-DPP-pipelined: R14 kernel + A-fragment prefetch (ds_read for
// tile-row i+1 issued before the j-loop of i, hiding ~120cyc LDS latency
// under the MFMA/exp body). Everything else identical.
// ---------------------------------------------------------------------------
__global__ __launch_bounds__(256) void tritt_k(
    const float* __restrict__ abcde, float* __restrict__ z)
{
    __shared__ __align__(16) unsigned short a_lds[TP * 64];
    __shared__ __align__(16) unsigned short b_lds[TP * 64];
    __shared__ float pl_s[4][TP];
    __shared__ float pr_s[4][TP];

    int tid = threadIdx.x, lane = tid & 63, wv = tid >> 6;
    int bh = blockIdx.y;
    int b = bh >> 2, h = bh & 3;
    const float* base = abcde + (long)b * TT * ABCDE_N;
    const float SC = 1.4426950408889634f / 64.f;   // log2(e)/DH

    // stage A and B once (bf16, swizzled)
    for (int i = tid; i < TP * 8; i += 256) {
        int row = i >> 3, ch = i & 7;
        int idx = row * 64 + ((ch * 8) ^ ((row & 7) << 3));
        unsigned short av[8], bv[8];
        if (row < TT) {
            const float* srcA = base + (long)row * ABCDE_N + h * 64 + ch * 8;
            const float* srcB = srcA + 256;
            float4 a0 = *(const float4*)(srcA);
            float4 a1 = *(const float4*)(srcA + 4);
            float4 b0 = *(const float4*)(srcB);
            float4 b1 = *(const float4*)(srcB + 4);
            av[0] = f2bf(a0.x); av[1] = f2bf(a0.y); av[2] = f2bf(a0.z); av[3] = f2bf(a0.w);
            av[4] = f2bf(a1.x); av[5] = f2bf(a1.y); av[6] = f2bf(a1.z); av[7] = f2bf(a1.w);
            bv[0] = f2bf(b0.x); bv[1] = f2bf(b0.y); bv[2] = f2bf(b0.z); bv[3] = f2bf(b0.w);
            bv[4] = f2bf(b1.x); bv[5] = f2bf(b1.y); bv[6] = f2bf(b1.z); bv[7] = f2bf(b1.w);
        } else {
#pragma unroll
            for (int j = 0; j < 8; j++) { av[j] = 0; bv[j] = 0; }
        }
        *(short8_t*)&a_lds[idx] = *(const short8_t*)av;
        *(short8_t*)&b_lds[idx] = *(const short8_t*)bv;
    }
    __syncthreads();

    int q = blockIdx.x * 4 + wv;
    if (q >= TT) return;

    int lm = lane & 15;
    int lg = lane >> 4;

    // c_q fragments in registers (SC folded)
    const float* cp = base + (long)q * ABCDE_N + 512 + h * 64;
    float c0[8], c1[8];
    {
        float4 v0 = *(const float4*)(cp + lg * 8);
        float4 v1 = *(const float4*)(cp + lg * 8 + 4);
        float4 v2 = *(const float4*)(cp + (lg + 4) * 8);
        float4 v3 = *(const float4*)(cp + (lg + 4) * 8 + 4);
        c0[0] = v0.x * SC; c0[1] = v0.y * SC; c0[2] = v0.z * SC; c0[3] = v0.w * SC;
        c0[4] = v1.x * SC; c0[5] = v1.y * SC; c0[6] = v1.z * SC; c0[7] = v1.w * SC;
        c1[0] = v2.x * SC; c1[1] = v2.y * SC; c1[2] = v2.z * SC; c1[3] = v2.w * SC;
        c1[4] = v3.x * SC; c1[5] = v3.y * SC; c1[6] = v3.z * SC; c1[7] = v3.w * SC;
    }

    // hoist all B fragments (26 x short8)
    short8_t bf0[NT16], bf1[NT16];
#pragma unroll
    for (int j = 0; j < NT16; j++) {
        int brow = j * 16 + lm;
        bf0[j] = *(const short8_t*)&b_lds[brow * 64 + (((lg    ) * 8) ^ ((brow & 7) << 3))];
        bf1[j] = *(const short8_t*)&b_lds[brow * 64 + (((lg + 4) * 8) ^ ((brow & 7) << 3))];
    }

    float pcol[NT16];
#pragma unroll
    for (int j = 0; j < NT16; j++) pcol[j] = 0.f;

    // prefetch i=0 A fragments
    int arow = lm;
    short8_t af0 = *(const short8_t*)&a_lds[arow * 64 + (((lg    ) * 8) ^ ((arow & 7) << 3))];
    short8_t af1 = *(const short8_t*)&a_lds[arow * 64 + (((lg + 4) * 8) ^ ((arow & 7) << 3))];

#pragma unroll 1
    for (int i = 0; i < NT16; i++) {
        // issue prefetch for i+1 before the compute body
        short8_t nf0 = af0, nf1 = af1;
        if (i + 1 < NT16) {
            int nrow = (i + 1) * 16 + lm;
            nf0 = *(const short8_t*)&a_lds[nrow * 64 + (((lg    ) * 8) ^ ((nrow & 7) << 3))];
            nf1 = *(const short8_t*)&a_lds[nrow * 64 + (((lg + 4) * 8) ^ ((nrow & 7) << 3))];
        }
        short8_t ac0, ac1;
#pragma unroll
        for (int e = 0; e < 8; e++) {
            ac0[e] = (short)f2bf(bf2f((unsigned short)af0[e]) * c0[e]);
            ac1[e] = (short)f2bf(bf2f((unsigned short)af1[e]) * c1[e]);
        }
        float prow[4] = {0.f, 0.f, 0.f, 0.f};
#pragma unroll
        for (int j = 0; j < NT16; j++) {
            f32x4 acc = {0.f, 0.f, 0.f, 0.f};
            acc = __builtin_amdgcn_mfma_f32_16x16x32_bf16(ac0, bf0[j], acc, 0, 0, 0);
            acc = __builtin_amdgcn_mfma_f32_16x16x32_bf16(ac1, bf1[j], acc, 0, 0, 0);
            float e0 = __builtin_amdgcn_exp2f(acc[0]);
            float e1 = __builtin_amdgcn_exp2f(acc[1]);
            float e2 = __builtin_amdgcn_exp2f(acc[2]);
            float e3 = __builtin_amdgcn_exp2f(acc[3]);
            prow[0] += e0; prow[1] += e1; prow[2] += e2; prow[3] += e3;
            pcol[j] += (e0 + e1) + (e2 + e3);
        }
#pragma unroll
        for (int r = 0; r < 4; r++) prow[r] = rowReduceSum16(prow[r]);
        if (lm == 0) {
            int rb = i * 16 + lg * 4;
#pragma unroll
            for (int r = 0; r < 4; r++) pl_s[wv][rb + r] = prow[r];
        }
        af0 = nf0; af1 = nf1;
    }
    // column marginals
#pragma unroll
    for (int j = 0; j < NT16; j++) {
        float c = pcol[j];
        c += __shfl_xor(c, 16, 64);
        c += __shfl_xor(c, 32, 64);
        if (lane < 16) pr_s[wv][j * 16 + lane] = c;
    }

    // Z (wave-local)
    float zpart = 0.f;
    for (int s = lane; s < TT; s += 64) zpart += pl_s[wv][s];
    zpart = waveReduceSum(zpart);
    float rz = 1.f / (zpart - 11.f * TT);

    // z = (pl_true @ d + pr_true @ e) * rz   (lane = dh), 4 FMA chains
    const float* dp = base + 768 + h * 64 + lane;
    const float* ep = base + 1024 + h * 64 + lane;
    float z0 = 0.f, z1 = 0.f, z2 = 0.f, z3 = 0.f;
    int s = 0;
    for (; s + 1 < TT; s += 2) {
        z0 = fmaf(pl_s[wv][s]     - 11.f, dp[(long)s * ABCDE_N],       z0);
        z1 = fmaf(pr_s[wv][s]     - 11.f, ep[(long)s * ABCDE_N],       z1);
        z2 = fmaf(pl_s[wv][s + 1] - 11.f, dp[(long)(s + 1) * ABCDE_N], z2);
        z3 = fmaf(pr_s[wv][s + 1] - 11.f, ep[(long)(s + 1) * ABCDE_N], z3);
    }
    z0 = fmaf(pl_s[wv][s] - 11.f, dp[(long)s * ABCDE_N], z0);   // s = 196
    z1 = fmaf(pr_s[wv][s] - 11.f, ep[(long)s * ABCDE_N], z1);
    z[((long)b * TT + q) * DIMM + h * 64 + lane] = ((z0 + z1) + (z2 + z3)) * rz;
}

// ---------------------------------------------------------------------------
extern "C" void kernel_launch(void* const* d_in, const int* in_sizes, int n_in,
                              void* d_out, int out_size, void* d_ws, size_t ws_size,
                              hipStream_t stream)
{
    const float* img    = (const float*)d_in[0];
    const float* g1     = (const float*)d_in[1];
    const float* b1     = (const float*)d_in[2];
    const float* pw     = (const float*)d_in[3];
    const float* pb     = (const float*)d_in[4];
    const float* g2     = (const float*)d_in[5];
    const float* b2     = (const float*)d_in[6];
    const float* pos    = (const float*)d_in[7];
    const float* cls    = (const float*)d_in[8];
    const float* attn_g = (const float*)d_in[9];
    const float* attn_b = (const float*)d_in[10];
    const float* w_abc  = (const float*)d_in[11];
    const float* b_abc  = (const float*)d_in[12];
    const float* w_out  = (const float*)d_in[13];
    const float* b_out  = (const float*)d_in[14];
    const float* ff_g   = (const float*)d_in[15];
    const float* ff_b   = (const float*)d_in[16];
    const float* w1     = (const float*)d_in[17];
    const float* b1f    = (const float*)d_in[18];
    const float* w2     = (const float*)d_in[19];
    const float* b2f    = (const float*)d_in[20];
    const float* fin_g  = (const float*)d_in[21];
    const float* fin_b  = (const float*)d_in[22];
    const float* hw     = (const float*)d_in[23];
    const float* hb     = (const float*)d_in[24];
    float* out = (float*)d_out;

    const int MROWS = BB * TT;  // 394
    float* ws = (float*)d_ws;
    float* xa = ws;                       // [394,256]
    float* xb = xa + (long)MROWS * DIMM;  // [394,256]
    float* zb = xb + (long)MROWS * DIMM;  // [394,256]
    float* ab = zb + (long)MROWS * DIMM;  // [394,1280] (also reused as [394,1024] h)

    patch_embed_k<<<99, 1024, 0, stream>>>(img, g1, b1, pw, pb, g2, b2, pos, cls, xa);

    const int GY = (MROWS + 3) / 4;         // 99
    const int QT4 = (TT + 3) / 4;           // 50
    for (int i = 0; i < 2; i++) {
        gemm_ksplit_k<<<dim3(ABCDE_N / 64, GY), 512, 0, stream>>>(
            xa, DIMM, MROWS, DIMM, ABCDE_N,
            w_abc + (long)i * DIMM * ABCDE_N, b_abc + (long)i * ABCDE_N,
            nullptr, ab, attn_g + i * DIMM, attn_b + i * DIMM, 0);
        tritt_k<<<dim3(QT4, BB * HEADS_), 256, 0, stream>>>(ab, zb);
        gemm_ksplit_k<<<dim3(DIMM / 64, GY), 512, 0, stream>>>(
            zb, DIMM, MROWS, DIMM, DIMM,
            w_out + (long)i * DIMM * DIMM, b_out + (long)i * DIMM,
            xa, xb, nullptr, nullptr, 0);
        gemm_ksplit_k<<<dim3(MLP_ / 64, GY), 512, 0, stream>>>(
            xb, DIMM, MROWS, DIMM, MLP_,
            w1 + (long)i * DIMM * MLP_, b1f + (long)i * MLP_,
            nullptr, ab, ff_g + i * DIMM, ff_b + i * DIMM, 1);
        gemm_ksplit_k<<<dim3(DIMM / 64, GY), 512, 0, stream>>>(
            ab, MLP_, MROWS, MLP_, DIMM,
            w2 + (long)i * MLP_ * DIMM, b2f + (long)i * DIMM,
            xb, xa, nullptr, nullptr, 0);
    }
    gemm_ksplit_k<<<dim3((NCLS_ + 63) / 64, 1), 512, 0, stream>>>(
        xa, (long)TT * DIMM, BB, DIMM, NCLS_,
        hw, hb, nullptr, out, fin_g, fin_b, 0);
}

// Round 16
// 195.830 us; speedup vs baseline: 1.4995x; 1.0785x over previous
//
#include <hip/hip_runtime.h>
#include <hip/hip_bf16.h>

// Dims
#define BB 2
#define TT 197
#define TP 208          // padded T (13*16)
#define NT16 13
#define DIMM 256
#define HEADS_ 4
#define DH_ 64
#define ABCDE_N 1280   // 5*HEADS*DH = 5*256
#define MLP_ 1024
#define NCLS_ 1000
#define PATCH_DIM_ 768

typedef __attribute__((ext_vector_type(8))) short short8_t;   // 8 bf16
typedef __attribute__((ext_vector_type(4))) float f32x4;

__device__ __forceinline__ float waveReduceSum(float v) {
#pragma unroll
    for (int off = 32; off > 0; off >>= 1) v += __shfl_xor(v, off, 64);
    return v;
}

// sum over the 16-lane row via DPP row_ror (no LDS)
__device__ __forceinline__ float rowReduceSum16(float v) {
    v += __uint_as_float(__builtin_amdgcn_update_dpp(
            0, __float_as_uint(v), 0x121, 0xF, 0xF, true));
    v += __uint_as_float(__builtin_amdgcn_update_dpp(
            0, __float_as_uint(v), 0x122, 0xF, 0xF, true));
    v += __uint_as_float(__builtin_amdgcn_update_dpp(
            0, __float_as_uint(v), 0x124, 0xF, 0xF, true));
    v += __uint_as_float(__builtin_amdgcn_update_dpp(
            0, __float_as_uint(v), 0x128, 0xF, 0xF, true));
    return v;
}

__device__ __forceinline__ unsigned short f2bf(float x) {
    unsigned int u = __float_as_uint(x);
    u += 0x7FFFu + ((u >> 16) & 1u);   // RNE
    return (unsigned short)(u >> 16);
}

__device__ __forceinline__ float bf2f(unsigned short u) {
    return __uint_as_float(((unsigned int)u) << 16);
}

// ---------------------------------------------------------------------------
// Patch embed v2 (unchanged from R15): 1024 threads, 4-way K-split.
// ---------------------------------------------------------------------------
__global__ __launch_bounds__(1024) void patch_embed_k(
    const float* __restrict__ img, const float* __restrict__ g1, const float* __restrict__ b1,
    const float* __restrict__ pw, const float* __restrict__ pb,
    const float* __restrict__ g2, const float* __restrict__ b2,
    const float* __restrict__ pos, const float* __restrict__ cls,
    float* __restrict__ xa)
{
    int tid = threadIdx.x;
    if (blockIdx.x == 98) {
        if (tid < DIMM)
            for (int b = 0; b < BB; b++)
                xa[(long)b * TT * DIMM + tid] = cls[tid] + pos[tid];
        return;
    }
    __shared__ __align__(16) float xs[4][PATCH_DIM_];
    __shared__ float psum[4][4][DIMM];   // [ks][row][col]
    __shared__ float red[8];
    int pr0 = blockIdx.x * 4;
    int wv16 = tid >> 6, lane = tid & 63;

    for (int i = tid; i < 4 * PATCH_DIM_; i += 1024) {
        int r = i / PATCH_DIM_, j = i - r * PATCH_DIM_;
        int pr = pr0 + r;
        int b = pr / 196, patch = pr % 196;
        int gh = patch / 14, gw = patch % 14;
        int c = j % 3, p2 = (j / 3) % 16, p1 = j / 48;
        xs[r][j] = img[(((long)b * 3 + c) * 224 + gh * 16 + p1) * 224 + gw * 16 + p2];
    }
    __syncthreads();
    if (wv16 < 4) {
        int r = wv16;
        float s = 0.f, s2 = 0.f;
        for (int j = lane; j < PATCH_DIM_; j += 64) { float v = xs[r][j]; s += v; s2 += v * v; }
        s = waveReduceSum(s); s2 = waveReduceSum(s2);
        float m = s / PATCH_DIM_;
        float rs = rsqrtf(s2 / PATCH_DIM_ - m * m + 1e-5f);
        for (int j = lane; j < PATCH_DIM_; j += 64)
            xs[r][j] = (xs[r][j] - m) * rs * g1[j] + b1[j];
    }
    __syncthreads();
    int col = tid & 255, ks = tid >> 8;
    int k0 = ks * (PATCH_DIM_ / 4);
    float acc[4] = {0.f, 0.f, 0.f, 0.f};
    for (int k = k0; k < k0 + PATCH_DIM_ / 4; k += 4) {
        float w0 = pw[(k + 0) * DIMM + col];
        float w1 = pw[(k + 1) * DIMM + col];
        float w2 = pw[(k + 2) * DIMM + col];
        float w3 = pw[(k + 3) * DIMM + col];
#pragma unroll
        for (int r = 0; r < 4; r++) {
            float4 xv = *(const float4*)&xs[r][k];
            acc[r] = fmaf(xv.x, w0, fmaf(xv.y, w1, fmaf(xv.z, w2, fmaf(xv.w, w3, acc[r]))));
        }
    }
#pragma unroll
    for (int r = 0; r < 4; r++) psum[ks][r][col] = acc[r];
    __syncthreads();

    float v4[4];
    if (tid < 256) {
#pragma unroll
        for (int r = 0; r < 4; r++)
            v4[r] = (psum[0][r][tid] + psum[1][r][tid])
                  + (psum[2][r][tid] + psum[3][r][tid]) + pb[tid];
    }
    for (int r = 0; r < 4; r++) {
        float s = 0.f, s2 = 0.f;
        if (tid < 256) {
            s = waveReduceSum(v4[r]);
            s2 = waveReduceSum(v4[r] * v4[r]);
            if (lane == 0) { red[wv16 * 2] = s; red[wv16 * 2 + 1] = s2; }
        }
        __syncthreads();
        float S = red[0] + red[2] + red[4] + red[6];
        float S2 = red[1] + red[3] + red[5] + red[7];
        __syncthreads();
        if (tid < 256) {
            float m = S / DIMM;
            float rs = rsqrtf(S2 / DIMM - m * m + 1e-5f);
            int pr = pr0 + r;
            int b = pr / 196, patch = pr % 196;
            float v = (v4[r] - m) * rs * g2[tid] + b2[tid] + pos[(1 + patch) * DIMM + tid];
            xa[((long)b * TT + 1 + patch) * DIMM + tid] = v;
        }
    }
}

// ---------------------------------------------------------------------------
// K-split GEMM v2 (unchanged): 512 threads, 8-way K-split, 64 cols/WG.
// Used for N=256 GEMMs (wout, ff2) and the head (keeps WG count up).
// ---------------------------------------------------------------------------
__global__ __launch_bounds__(512) void gemm_ksplit_k(
    const float* __restrict__ x, long x_stride, int M, int K, int N,
    const float* __restrict__ w, const float* __restrict__ bias,
    const float* __restrict__ res, float* __restrict__ out,
    const float* __restrict__ ln_g, const float* __restrict__ ln_b,
    int do_gelu)
{
    __shared__ __align__(16) float xs[4 * 1024];
    __shared__ float psum[8 * 4 * 64];   // [wave][row][col]
    int tid = threadIdx.x, lane = tid & 63, wv = tid >> 6;   // wv 0..7
    int row0 = blockIdx.y * 4, col0 = blockIdx.x * 64;

    for (int i = tid; i < 4 * K; i += 512) {
        int r = i / K, k = i - r * K;
        int row = row0 + r;
        xs[i] = (row < M) ? x[(long)row * x_stride + k] : 0.f;
    }
    __syncthreads();
    if (ln_g) {
        if (wv < 4) {
            float* xr = xs + wv * K;
            float s = 0.f, s2 = 0.f;
            for (int k = lane; k < K; k += 64) { float v = xr[k]; s += v; s2 += v * v; }
            s = waveReduceSum(s); s2 = waveReduceSum(s2);
            float m = s / K;
            float rs = rsqrtf(s2 / K - m * m + 1e-5f);
            for (int k = lane; k < K; k += 64)
                xr[k] = (xr[k] - m) * rs * ln_g[k] + ln_b[k];
        }
        __syncthreads();
    }

    int col = col0 + lane;
    float a0 = 0.f, a1 = 0.f, a2 = 0.f, a3 = 0.f;
    int kq = K >> 3;
    if (col < N) {
        const float* x0 = xs + wv * kq;
        const float* x1 = x0 + K;
        const float* x2 = x1 + K;
        const float* x3 = x2 + K;
        const float* wp = w + (long)(wv * kq) * N + col;
        long nl = N;
        for (int kk = 0; kk < kq; kk += 4) {
            float w0 = wp[0], w1 = wp[nl], w2 = wp[2 * nl], w3 = wp[3 * nl];
            wp += 4 * nl;
            float4 v0 = *(const float4*)(x0 + kk);
            float4 v1 = *(const float4*)(x1 + kk);
            float4 v2 = *(const float4*)(x2 + kk);
            float4 v3 = *(const float4*)(x3 + kk);
            a0 = fmaf(v0.x, w0, fmaf(v0.y, w1, fmaf(v0.z, w2, fmaf(v0.w, w3, a0))));
            a1 = fmaf(v1.x, w0, fmaf(v1.y, w1, fmaf(v1.z, w2, fmaf(v1.w, w3, a1))));
            a2 = fmaf(v2.x, w0, fmaf(v2.y, w1, fmaf(v2.z, w2, fmaf(v2.w, w3, a2))));
            a3 = fmaf(v3.x, w0, fmaf(v3.y, w1, fmaf(v3.z, w2, fmaf(v3.w, w3, a3))));
        }
    }
    psum[wv * 256 + 0 * 64 + lane] = a0;
    psum[wv * 256 + 1 * 64 + lane] = a1;
    psum[wv * 256 + 2 * 64 + lane] = a2;
    psum[wv * 256 + 3 * 64 + lane] = a3;
    __syncthreads();

    if (tid < 256) {
        int r = tid >> 6, c = tid & 63;
        float v = ((psum[r * 64 + c]        + psum[256 + r * 64 + c])
                +  (psum[512 + r * 64 + c]  + psum[768 + r * 64 + c]))
                + ((psum[1024 + r * 64 + c] + psum[1280 + r * 64 + c])
                +  (psum[1536 + r * 64 + c] + psum[1792 + r * 64 + c]));
        int row = row0 + r, cw = col0 + c;
        if (row < M && cw < N) {
            if (bias) v += bias[cw];
            if (do_gelu) v = 0.5f * v * (1.f + erff(v * 0.70710678118654752f));
            if (res) v += res[(long)row * N + cw];
            out[(long)row * N + cw] = v;
        }
    }
}

// ---------------------------------------------------------------------------
// K-split GEMM v3 "wide": 512 threads, 8-way K-split, 4 cols/thread
// (256 cols/WG). Same 4 ds_read_b128/iter amortized over 64 FMAs ->
// LDS-pipe issue /4 vs v2. Requires N % 256 == 0 (abcde N=1280, ff1 N=1024).
// Grid (N/256, ceil(M/4)).
// ---------------------------------------------------------------------------
__global__ __launch_bounds__(512) void gemm_ksplit4_k(
    const float* __restrict__ x, long x_stride, int M, int K, int N,
    const float* __restrict__ w, const float* __restrict__ bias,
    const float* __restrict__ res, float* __restrict__ out,
    const float* __restrict__ ln_g, const float* __restrict__ ln_b,
    int do_gelu)
{
    __shared__ __align__(16) float xs[4 * 1024];
    __shared__ float psum[8 * 4 * 256];   // [wave][row][col] 32KB
    int tid = threadIdx.x, lane = tid & 63, wv = tid >> 6;   // wv 0..7
    int row0 = blockIdx.y * 4, col0 = blockIdx.x * 256;

    for (int i = tid; i < 4 * K; i += 512) {
        int r = i / K, k = i - r * K;
        int row = row0 + r;
        xs[i] = (row < M) ? x[(long)row * x_stride + k] : 0.f;
    }
    __syncthreads();
    if (ln_g) {
        if (wv < 4) {
            float* xr = xs + wv * K;
            float s = 0.f, s2 = 0.f;
            for (int k = lane; k < K; k += 64) { float v = xr[k]; s += v; s2 += v * v; }
            s = waveReduceSum(s); s2 = waveReduceSum(s2);
            float m = s / K;
            float rs = rsqrtf(s2 / K - m * m + 1e-5f);
            for (int k = lane; k < K; k += 64)
                xr[k] = (xr[k] - m) * rs * ln_g[k] + ln_b[k];
        }
        __syncthreads();
    }

    int kq = K >> 3;
    float acc[4][4];   // [row][colblk]
#pragma unroll
    for (int r = 0; r < 4; r++)
#pragma unroll
        for (int c = 0; c < 4; c++) acc[r][c] = 0.f;
    {
        const float* x0 = xs + wv * kq;
        const float* x1 = x0 + K;
        const float* x2 = x1 + K;
        const float* x3 = x2 + K;
        const float* wp = w + (long)(wv * kq) * N + col0 + lane;
        long nl = N;
        for (int kk = 0; kk < kq; kk += 2) {
            float wk0[4], wk1[4];
#pragma unroll
            for (int c = 0; c < 4; c++) {
                wk0[c] = wp[c * 64];
                wk1[c] = wp[nl + c * 64];
            }
            wp += 2 * nl;
            float2 v0 = *(const float2*)(x0 + kk);
            float2 v1 = *(const float2*)(x1 + kk);
            float2 v2 = *(const float2*)(x2 + kk);
            float2 v3 = *(const float2*)(x3 + kk);
#pragma unroll
            for (int c = 0; c < 4; c++) {
                acc[0][c] = fmaf(v0.x, wk0[c], fmaf(v0.y, wk1[c], acc[0][c]));
                acc[1][c] = fmaf(v1.x, wk0[c], fmaf(v1.y, wk1[c], acc[1][c]));
                acc[2][c] = fmaf(v2.x, wk0[c], fmaf(v2.y, wk1[c], acc[2][c]));
                acc[3][c] = fmaf(v3.x, wk0[c], fmaf(v3.y, wk1[c], acc[3][c]));
            }
        }
    }
#pragma unroll
    for (int r = 0; r < 4; r++)
#pragma unroll
        for (int c = 0; c < 4; c++)
            psum[wv * 1024 + r * 256 + c * 64 + lane] = acc[r][c];
    __syncthreads();

    // reduce: 1024 outputs over 512 threads (2 each)
    for (int idx = tid; idx < 1024; idx += 512) {
        int r = idx >> 8, c = idx & 255;
        float v = ((psum[r * 256 + c]        + psum[1024 + r * 256 + c])
                +  (psum[2048 + r * 256 + c] + psum[3072 + r * 256 + c]))
                + ((psum[4096 + r * 256 + c] + psum[5120 + r * 256 + c])
                +  (psum[6144 + r * 256 + c] + psum[7168 + r * 256 + c]));
        int row = row0 + r, cw = col0 + c;
        if (row < M && cw < N) {
            if (bias) v += bias[cw];
            if (do_gelu) v = 0.5f * v * (1.f + erff(v * 0.70710678118654752f));
            if (res) v += res[(long)row * N + cw];
            out[(long)row * N + cw] = v;
        }
    }
}

// ---------------------------------------------------------------------------
// Trittention v3-DPP-pipelined (unchanged from R15, 46.6us/dispatch).
// ---------------------------------------------------------------------------
__global__ __launch_bounds__(256) void tritt_k(
    const float* __restrict__ abcde, float* __restrict__ z)
{
    __shared__ __align__(16) unsigned short a_lds[TP * 64];
    __shared__ __align__(16) unsigned short b_lds[TP * 64];
    __shared__ float pl_s[4][TP];
    __shared__ float pr_s[4][TP];

    int tid = threadIdx.x, lane = tid & 63, wv = tid >> 6;
    int bh = blockIdx.y;
    int b = bh >> 2, h = bh & 3;
    const float* base = abcde + (long)b * TT * ABCDE_N;
    const float SC = 1.4426950408889634f / 64.f;   // log2(e)/DH

    for (int i = tid; i < TP * 8; i += 256) {
        int row = i >> 3, ch = i & 7;
        int idx = row * 64 + ((ch * 8) ^ ((row & 7) << 3));
        unsigned short av[8], bv[8];
        if (row < TT) {
            const float* srcA = base + (long)row * ABCDE_N + h * 64 + ch * 8;
            const float* srcB = srcA + 256;
            float4 a0 = *(const float4*)(srcA);
            float4 a1 = *(const float4*)(srcA + 4);
            float4 b0 = *(const float4*)(srcB);
            float4 b1 = *(const float4*)(srcB + 4);
            av[0] = f2bf(a0.x); av[1] = f2bf(a0.y); av[2] = f2bf(a0.z); av[3] = f2bf(a0.w);
            av[4] = f2bf(a1.x); av[5] = f2bf(a1.y); av[6] = f2bf(a1.z); av[7] = f2bf(a1.w);
            bv[0] = f2bf(b0.x); bv[1] = f2bf(b0.y); bv[2] = f2bf(b0.z); bv[3] = f2bf(b0.w);
            bv[4] = f2bf(b1.x); bv[5] = f2bf(b1.y); bv[6] = f2bf(b1.z); bv[7] = f2bf(b1.w);
        } else {
#pragma unroll
            for (int j = 0; j < 8; j++) { av[j] = 0; bv[j] = 0; }
        }
        *(short8_t*)&a_lds[idx] = *(const short8_t*)av;
        *(short8_t*)&b_lds[idx] = *(const short8_t*)bv;
    }
    __syncthreads();

    int q = blockIdx.x * 4 + wv;
    if (q >= TT) return;

    int lm = lane & 15;
    int lg = lane >> 4;

    const float* cp = base + (long)q * ABCDE_N + 512 + h * 64;
    float c0[8], c1[8];
    {
        float4 v0 = *(const float4*)(cp + lg * 8);
        float4 v1 = *(const float4*)(cp + lg * 8 + 4);
        float4 v2 = *(const float4*)(cp + (lg + 4) * 8);
        float4 v3 = *(const float4*)(cp + (lg + 4) * 8 + 4);
        c0[0] = v0.x * SC; c0[1] = v0.y * SC; c0[2] = v0.z * SC; c0[3] = v0.w * SC;
        c0[4] = v1.x * SC; c0[5] = v1.y * SC; c0[6] = v1.z * SC; c0[7] = v1.w * SC;
        c1[0] = v2.x * SC; c1[1] = v2.y * SC; c1[2] = v2.z * SC; c1[3] = v2.w * SC;
        c1[4] = v3.x * SC; c1[5] = v3.y * SC; c1[6] = v3.z * SC; c1[7] = v3.w * SC;
    }

    short8_t bf0[NT16], bf1[NT16];
#pragma unroll
    for (int j = 0; j < NT16; j++) {
        int brow = j * 16 + lm;
        bf0[j] = *(const short8_t*)&b_lds[brow * 64 + (((lg    ) * 8) ^ ((brow & 7) << 3))];
        bf1[j] = *(const short8_t*)&b_lds[brow * 64 + (((lg + 4) * 8) ^ ((brow & 7) << 3))];
    }

    float pcol[NT16];
#pragma unroll
    for (int j = 0; j < NT16; j++) pcol[j] = 0.f;

    int arow = lm;
    short8_t af0 = *(const short8_t*)&a_lds[arow * 64 + (((lg    ) * 8) ^ ((arow & 7) << 3))];
    short8_t af1 = *(const short8_t*)&a_lds[arow * 64 + (((lg + 4) * 8) ^ ((arow & 7) << 3))];

#pragma unroll 1
    for (int i = 0; i < NT16; i++) {
        short8_t nf0 = af0, nf1 = af1;
        if (i + 1 < NT16) {
            int nrow = (i + 1) * 16 + lm;
            nf0 = *(const short8_t*)&a_lds[nrow * 64 + (((lg    ) * 8) ^ ((nrow & 7) << 3))];
            nf1 = *(const short8_t*)&a_lds[nrow * 64 + (((lg + 4) * 8) ^ ((nrow & 7) << 3))];
        }
        short8_t ac0, ac1;
#pragma unroll
        for (int e = 0; e < 8; e++) {
            ac0[e] = (short)f2bf(bf2f((unsigned short)af0[e]) * c0[e]);
            ac1[e] = (short)f2bf(bf2f((unsigned short)af1[e]) * c1[e]);
        }
        float prow[4] = {0.f, 0.f, 0.f, 0.f};
#pragma unroll
        for (int j = 0; j < NT16; j++) {
            f32x4 acc = {0.f, 0.f, 0.f, 0.f};
            acc = __builtin_amdgcn_mfma_f32_16x16x32_bf16(ac0, bf0[j], acc, 0, 0, 0);
            acc = __builtin_amdgcn_mfma_f32_16x16x32_bf16(ac1, bf1[j], acc, 0, 0, 0);
            float e0 = __builtin_amdgcn_exp2f(acc[0]);
            float e1 = __builtin_amdgcn_exp2f(acc[1]);
            float e2 = __builtin_amdgcn_exp2f(acc[2]);
            float e3 = __builtin_amdgcn_exp2f(acc[3]);
            prow[0] += e0; prow[1] += e1; prow[2] += e2; prow[3] += e3;
            pcol[j] += (e0 + e1) + (e2 + e3);
        }
#pragma unroll
        for (int r = 0; r < 4; r++) prow[r] = rowReduceSum16(prow[r]);
        if (lm == 0) {
            int rb = i * 16 + lg * 4;
#pragma unroll
            for (int r = 0; r < 4; r++) pl_s[wv][rb + r] = prow[r];
        }
        af0 = nf0; af1 = nf1;
    }
#pragma unroll
    for (int j = 0; j < NT16; j++) {
        float c = pcol[j];
        c += __shfl_xor(c, 16, 64);
        c += __shfl_xor(c, 32, 64);
        if (lane < 16) pr_s[wv][j * 16 + lane] = c;
    }

    float zpart = 0.f;
    for (int s = lane; s < TT; s += 64) zpart += pl_s[wv][s];
    zpart = waveReduceSum(zpart);
    float rz = 1.f / (zpart - 11.f * TT);

    const float* dp = base + 768 + h * 64 + lane;
    const float* ep = base + 1024 + h * 64 + lane;
    float z0 = 0.f, z1 = 0.f, z2 = 0.f, z3 = 0.f;
    int s = 0;
    for (; s + 1 < TT; s += 2) {
        z0 = fmaf(pl_s[wv][s]     - 11.f, dp[(long)s * ABCDE_N],       z0);
        z1 = fmaf(pr_s[wv][s]     - 11.f, ep[(long)s * ABCDE_N],       z1);
        z2 = fmaf(pl_s[wv][s + 1] - 11.f, dp[(long)(s + 1) * ABCDE_N], z2);
        z3 = fmaf(pr_s[wv][s + 1] - 11.f, ep[(long)(s + 1) * ABCDE_N], z3);
    }
    z0 = fmaf(pl_s[wv][s] - 11.f, dp[(long)s * ABCDE_N], z0);   // s = 196
    z1 = fmaf(pr_s[wv][s] - 11.f, ep[(long)s * ABCDE_N], z1);
    z[((long)b * TT + q) * DIMM + h * 64 + lane] = ((z0 + z1) + (z2 + z3)) * rz;
}

// ---------------------------------------------------------------------------
extern "C" void kernel_launch(void* const* d_in, const int* in_sizes, int n_in,
                              void* d_out, int out_size, void* d_ws, size_t ws_size,
                              hipStream_t stream)
{
    const float* img    = (const float*)d_in[0];
    const float* g1     = (const float*)d_in[1];
    const float* b1     = (const float*)d_in[2];
    const float* pw     = (const float*)d_in[3];
    const float* pb     = (const float*)d_in[4];
    const float* g2     = (const float*)d_in[5];
    const float* b2     = (const float*)d_in[6];
    const float* pos    = (const float*)d_in[7];
    const float* cls    = (const float*)d_in[8];
    const float* attn_g = (const float*)d_in[9];
    const float* attn_b = (const float*)d_in[10];
    const float* w_abc  = (const float*)d_in[11];
    const float* b_abc  = (const float*)d_in[12];
    const float* w_out  = (const float*)d_in[13];
    const float* b_out  = (const float*)d_in[14];
    const float* ff_g   = (const float*)d_in[15];
    const float* ff_b   = (const float*)d_in[16];
    const float* w1     = (const float*)d_in[17];
    const float* b1f    = (const float*)d_in[18];
    const float* w2     = (const float*)d_in[19];
    const float* b2f    = (const float*)d_in[20];
    const float* fin_g  = (const float*)d_in[21];
    const float* fin_b  = (const float*)d_in[22];
    const float* hw     = (const float*)d_in[23];
    const float* hb     = (const float*)d_in[24];
    float* out = (float*)d_out;

    const int MROWS = BB * TT;  // 394
    float* ws = (float*)d_ws;
    float* xa = ws;                       // [394,256]
    float* xb = xa + (long)MROWS * DIMM;  // [394,256]
    float* zb = xb + (long)MROWS * DIMM;  // [394,256]
    float* ab = zb + (long)MROWS * DIMM;  // [394,1280] (also reused as [394,1024] h)

    patch_embed_k<<<99, 1024, 0, stream>>>(img, g1, b1, pw, pb, g2, b2, pos, cls, xa);

    const int GY = (MROWS + 3) / 4;         // 99
    const int QT4 = (TT + 3) / 4;           // 50
    for (int i = 0; i < 2; i++) {
        // abcde = LN(xa) @ w_abcde + b (wide kernel, N=1280 -> grid 5x99)
        gemm_ksplit4_k<<<dim3(ABCDE_N / 256, GY), 512, 0, stream>>>(
            xa, DIMM, MROWS, DIMM, ABCDE_N,
            w_abc + (long)i * DIMM * ABCDE_N, b_abc + (long)i * ABCDE_N,
            nullptr, ab, attn_g + i * DIMM, attn_b + i * DIMM, 0);
        tritt_k<<<dim3(QT4, BB * HEADS_), 256, 0, stream>>>(ab, zb);
        gemm_ksplit_k<<<dim3(DIMM / 64, GY), 512, 0, stream>>>(
            zb, DIMM, MROWS, DIMM, DIMM,
            w_out + (long)i * DIMM * DIMM, b_out + (long)i * DIMM,
            xa, xb, nullptr, nullptr, 0);
        // h = gelu(LN(xb) @ w1 + b1) (wide kernel, N=1024 -> grid 4x99)
        gemm_ksplit4_k<<<dim3(MLP_ / 256, GY), 512, 0, stream>>>(
            xb, DIMM, MROWS, DIMM, MLP_,
            w1 + (long)i * DIMM * MLP_, b1f + (long)i * MLP_,
            nullptr, ab, ff_g + i * DIMM, ff_b + i * DIMM, 1);
        gemm_ksplit_k<<<dim3(DIMM / 64, GY), 512, 0, stream>>>(
            ab, MLP_, MROWS, MLP_, DIMM,
            w2 + (long)i * MLP_ * DIMM, b2f + (long)i * DIMM,
            xb, xa, nullptr, nullptr, 0);
    }
    gemm_ksplit_k<<<dim3((NCLS_ + 63) / 64, 1), 512, 0, stream>>>(
        xa, (long)TT * DIMM, BB, DIMM, NCLS_,
        hw, hb, nullptr, out, fin_g, fin_b, 0);
}